// Round 1
// baseline (1062.714 us; speedup 1.0000x reference)
//
#include <hip/hip_runtime.h>

#define DEV __device__ __forceinline__

using short8  = __attribute__((ext_vector_type(8))) short;
using floatx4 = __attribute__((ext_vector_type(4))) float;

// f32 -> bf16 round-to-nearest-even on raw bits
DEV unsigned short f2bf(float f) {
  unsigned int u = __float_as_uint(f);
  u += 0x7FFFu + ((u >> 16) & 1u);
  return (unsigned short)(u >> 16);
}

DEV void stage16(void* lds, const void* g) {
#if defined(__has_builtin) && __has_builtin(__builtin_amdgcn_global_load_lds)
  __builtin_amdgcn_global_load_lds(
      (__attribute__((address_space(1))) void*)g,
      (__attribute__((address_space(3))) void*)lds, 16, 0, 0);
#else
  *(int4*)lds = *(const int4*)g;
#endif
}

DEV float wave_sum(float x) {
#pragma unroll
  for (int m = 32; m; m >>= 1) x += __shfl_xor(x, m);
  return x;
}
DEV float wave_max(float x) {
#pragma unroll
  for (int m = 32; m; m >>= 1) x = fmaxf(x, __shfl_xor(x, m));
  return x;
}

// ---------------------------------------------------------------------------
// GEMM: C[z] = A[z] (MxK, K-major) * Bt[z]^T (Bt is NxK, K-major) + bias
// Outputs optional: Cf (f32), Cb (bf16), C2 (f32 res path, ld=2048, +offc2).
// M,N multiples of 128; K multiple of 32.
// ---------------------------------------------------------------------------
#define BM 128
#define BN 128
#define BK 32

__global__ __launch_bounds__(256)
void gemm_bt(const short* __restrict__ A, long long sAz,
             const short* __restrict__ Bt, long long sBz,
             const float* __restrict__ bias,
             float* __restrict__ Cf, long long sCfz,
             short* __restrict__ Cb, long long sCbz,
             float* __restrict__ C2, int offc2,
             int M, int N, int K) {
  const int z = blockIdx.z;
  A  += (long long)z * sAz;
  Bt += (long long)z * sBz;
  float* Cfz = Cf ? Cf + (long long)z * sCfz : (float*)0;
  short* Cbz = Cb ? Cb + (long long)z * sCbz : (short*)0;

  const int m0 = blockIdx.y * BM;
  const int n0 = blockIdx.x * BN;

  __shared__ __align__(16) short As[BM * BK];
  __shared__ __align__(16) short Bs[BN * BK];

  const int t    = threadIdx.x;
  const int lane = t & 63;
  const int w    = t >> 6;
  const int wr   = (w >> 1) * 64;   // wave row origin in 128x128 tile
  const int wc   = (w & 1) * 64;    // wave col origin
  const int mr   = lane & 15;
  const int kq   = lane >> 4;       // quad id 0..3

  floatx4 acc[4][4];
#pragma unroll
  for (int i = 0; i < 4; ++i)
#pragma unroll
    for (int j = 0; j < 4; ++j)
      acc[i][j] = (floatx4){0.f, 0.f, 0.f, 0.f};

  for (int k0 = 0; k0 < K; k0 += BK) {
    // stage 128x32 bf16 tiles of A and Bt; chunk c -> LDS offset c*16B
    // (global_load_lds needs wave-uniform base + lane*16: c = t + i*256 ok)
#pragma unroll
    for (int i = 0; i < 2; ++i) {
      const int c   = t + i * 256;
      const int row = c >> 2;
      const int cc  = c & 3;
      stage16(&As[c * 8], A  + (size_t)(m0 + row) * K + k0 + cc * 8);
      stage16(&Bs[c * 8], Bt + (size_t)(n0 + row) * K + k0 + cc * 8);
    }
    __syncthreads();  // compiler emits s_waitcnt vmcnt(0) before s_barrier

    short8 af[4], bf[4];
#pragma unroll
    for (int i = 0; i < 4; ++i)
      af[i] = *(const short8*)&As[(wr + i * 16 + mr) * BK + kq * 8];
#pragma unroll
    for (int j = 0; j < 4; ++j)
      bf[j] = *(const short8*)&Bs[(wc + j * 16 + mr) * BK + kq * 8];
#pragma unroll
    for (int i = 0; i < 4; ++i)
#pragma unroll
      for (int j = 0; j < 4; ++j)
        acc[i][j] = __builtin_amdgcn_mfma_f32_16x16x32_bf16(af[i], bf[j], acc[i][j], 0, 0, 0);
    __syncthreads();
  }

  // Epilogue: D layout col=lane&15, row=(lane>>4)*4+reg  [measured m89/m91]
#pragma unroll
  for (int i = 0; i < 4; ++i) {
#pragma unroll
    for (int r = 0; r < 4; ++r) {
      const int row = m0 + wr + i * 16 + kq * 4 + r;
#pragma unroll
      for (int j = 0; j < 4; ++j) {
        const int col = n0 + wc + j * 16 + mr;
        float vv = acc[i][j][r];
        if (bias) vv += bias[col];
        if (Cfz) Cfz[(size_t)row * N + col] = vv;
        if (Cbz) Cbz[(size_t)row * N + col] = (short)f2bf(vv);
        if (C2)  C2[(size_t)row * 2048 + offc2 + col] = vv;
      }
    }
  }
}

// ---------------------------------------------------------------------------
// LayerNorm over D=1024, f32 in -> bf16 out, with output scale (q gets 1/32)
// ---------------------------------------------------------------------------
__global__ __launch_bounds__(256)
void ln_kernel(const float* __restrict__ x, const float* __restrict__ gw,
               const float* __restrict__ bw, unsigned short* __restrict__ y,
               float scale) {
  const int row = blockIdx.x, t = threadIdx.x;
  const float4 v = ((const float4*)(x + (size_t)row * 1024))[t];
  float s  = v.x + v.y + v.z + v.w;
  float s2 = v.x * v.x + v.y * v.y + v.z * v.z + v.w * v.w;
  s = wave_sum(s);
  s2 = wave_sum(s2);
  __shared__ float r1[4], r2[4];
  const int w = t >> 6, lane = t & 63;
  if (!lane) { r1[w] = s; r2[w] = s2; }
  __syncthreads();
  s  = r1[0] + r1[1] + r1[2] + r1[3];
  s2 = r2[0] + r2[1] + r2[2] + r2[3];
  const float mean = s * (1.f / 1024.f);
  const float var  = s2 * (1.f / 1024.f) - mean * mean;
  const float rstd = 1.f / sqrtf(var + 1e-6f);
  const float4 g4 = ((const float4*)gw)[t];
  const float4 b4 = ((const float4*)bw)[t];
  ushort4 o;
  o.x = f2bf(((v.x - mean) * rstd * g4.x + b4.x) * scale);
  o.y = f2bf(((v.y - mean) * rstd * g4.y + b4.y) * scale);
  o.z = f2bf(((v.z - mean) * rstd * g4.z + b4.z) * scale);
  o.w = f2bf(((v.w - mean) * rstd * g4.w + b4.w) * scale);
  ((ushort4*)(y + (size_t)row * 1024))[t] = o;
}

// ---------------------------------------------------------------------------
// Row softmax over 2048 f32 -> bf16 P (+ optional f32 copy for a2 output)
// ---------------------------------------------------------------------------
__global__ __launch_bounds__(256)
void softmax_kernel(const float* __restrict__ S, unsigned short* __restrict__ P,
                    float* __restrict__ A2) {
  const int row = blockIdx.x, t = threadIdx.x;
  const float4* sr = (const float4*)(S + (size_t)row * 2048);
  float4 a = sr[t], b = sr[t + 256];
  float m = fmaxf(fmaxf(fmaxf(a.x, a.y), fmaxf(a.z, a.w)),
                  fmaxf(fmaxf(b.x, b.y), fmaxf(b.z, b.w)));
  m = wave_max(m);
  __shared__ float red[4];
  const int w = t >> 6, lane = t & 63;
  if (!lane) red[w] = m;
  __syncthreads();
  m = fmaxf(fmaxf(red[0], red[1]), fmaxf(red[2], red[3]));
  a.x = expf(a.x - m); a.y = expf(a.y - m); a.z = expf(a.z - m); a.w = expf(a.w - m);
  b.x = expf(b.x - m); b.y = expf(b.y - m); b.z = expf(b.z - m); b.w = expf(b.w - m);
  float s = a.x + a.y + a.z + a.w + b.x + b.y + b.z + b.w;
  s = wave_sum(s);
  __syncthreads();
  if (!lane) red[w] = s;
  __syncthreads();
  s = red[0] + red[1] + red[2] + red[3];
  const float inv = 1.f / s;
  a.x *= inv; a.y *= inv; a.z *= inv; a.w *= inv;
  b.x *= inv; b.y *= inv; b.z *= inv; b.w *= inv;
  ushort4 o0, o1;
  o0.x = f2bf(a.x); o0.y = f2bf(a.y); o0.z = f2bf(a.z); o0.w = f2bf(a.w);
  o1.x = f2bf(b.x); o1.y = f2bf(b.y); o1.z = f2bf(b.z); o1.w = f2bf(b.w);
  ((ushort4*)(P + (size_t)row * 2048))[t] = o0;
  ((ushort4*)(P + (size_t)row * 2048))[t + 256] = o1;
  if (A2) {
    float4* ar = (float4*)(A2 + (size_t)row * 2048);
    ar[t] = a;
    ar[t + 256] = b;
  }
}

// ---------------------------------------------------------------------------
// f32 -> bf16 cast (vectorized)
// ---------------------------------------------------------------------------
__global__ __launch_bounds__(256)
void cast_kernel(const float* __restrict__ x, unsigned short* __restrict__ y, int n4) {
  const int i = blockIdx.x * 256 + threadIdx.x;
  if (i >= n4) return;
  const float4 v = ((const float4*)x)[i];
  ushort4 o;
  o.x = f2bf(v.x); o.y = f2bf(v.y); o.z = f2bf(v.z); o.w = f2bf(v.w);
  ((ushort4*)y)[i] = o;
}

// ---------------------------------------------------------------------------
// W (1024x1024 f32) -> W^T (1024x1024 bf16)
// ---------------------------------------------------------------------------
__global__ __launch_bounds__(256)
void transpose_w_kernel(const float* __restrict__ in, unsigned short* __restrict__ out) {
  __shared__ unsigned short tile[64][65];
  const int tr0 = blockIdx.y * 64, tc0 = blockIdx.x * 64;
  const int x = threadIdx.x & 63, y = threadIdx.x >> 6;
#pragma unroll
  for (int i = 0; i < 16; ++i) {
    const int r = i * 4 + y;
    tile[r][x] = f2bf(in[(size_t)(tr0 + r) * 1024 + tc0 + x]);
  }
  __syncthreads();
#pragma unroll
  for (int i = 0; i < 16; ++i) {
    const int r = i * 4 + y;
    out[(size_t)(tc0 + r) * 1024 + tr0 + x] = tile[x][r];
  }
}

// ---------------------------------------------------------------------------
// per-batch bf16 transpose: in (z,2048,1024) -> out (z,1024,2048)
// ---------------------------------------------------------------------------
__global__ __launch_bounds__(256)
void transpose_v_kernel(const unsigned short* __restrict__ in, unsigned short* __restrict__ out) {
  __shared__ unsigned short tile[64][65];
  in  += (size_t)blockIdx.z * 2048 * 1024;
  out += (size_t)blockIdx.z * 1024 * 2048;
  const int tr0 = blockIdx.y * 64, tc0 = blockIdx.x * 64;
  const int x = threadIdx.x & 63, y = threadIdx.x >> 6;
#pragma unroll
  for (int i = 0; i < 16; ++i) {
    const int r = i * 4 + y;
    tile[r][x] = in[(size_t)(tr0 + r) * 1024 + tc0 + x];
  }
  __syncthreads();
#pragma unroll
  for (int i = 0; i < 16; ++i) {
    const int r = i * 4 + y;
    out[(size_t)(tc0 + r) * 2048 + tr0 + x] = tile[x][r];
  }
}

// ---------------------------------------------------------------------------
extern "C" void kernel_launch(void* const* d_in, const int* in_sizes, int n_in,
                              void* d_out, int out_size, void* d_ws, size_t ws_size,
                              hipStream_t stream) {
  // inputs: 0 q, 1 k, 2 v, then (W, b) x8: Wq1 bq1 Wk1 bk1 Wv1 bv1 Wf1 bf1
  //                                        Wq2 bq2 Wk2 bk2 Wv2 bv2 Wf2 bf2
  // then (g, B) x6: q1 k1 v1 q2 k2 v2
  const float* q = (const float*)d_in[0];
  const float* k = (const float*)d_in[1];
  const float* v = (const float*)d_in[2];
  const float* W[8];
  const float* bW[8];
  for (int i = 0; i < 8; ++i) {
    W[i]  = (const float*)d_in[3 + 2 * i];
    bW[i] = (const float*)d_in[4 + 2 * i];
  }
  const float* g_[6];
  const float* B_[6];
  for (int i = 0; i < 6; ++i) {
    g_[i] = (const float*)d_in[19 + 2 * i];
    B_[i] = (const float*)d_in[20 + 2 * i];
  }

  float* out_p = (float*)d_out;          // (4,2048,1024)
  float* res_p = out_p + 8388608;        // (4,2048,1,2048) = (8192,2048)
  float* a2_p  = res_p + 16777216;       // (4,2048,2048)

  // workspace layout (240 MB, phase-aliased)
  char* ws = (char*)d_ws;
  const size_t MBy = 1u << 20;
  unsigned short* WT   = (unsigned short*)ws;                 // 8 x 2MB
  unsigned short* kb   = (unsigned short*)(ws + 16 * MBy);
  unsigned short* vb   = (unsigned short*)(ws + 32 * MBy);
  unsigned short* lnq  = (unsigned short*)(ws + 48 * MBy);
  unsigned short* lnk  = (unsigned short*)(ws + 64 * MBy);
  unsigned short* lnv  = (unsigned short*)(ws + 80 * MBy);
  unsigned short* lnvT = (unsigned short*)(ws + 96 * MBy);
  unsigned short* ofb  = (unsigned short*)(ws + 112 * MBy);
  unsigned short* ob   = (unsigned short*)(ws + 128 * MBy);   // qb, then o1b/o2b
  float* Sbuf = (float*)(ws + 144 * MBy);                     // 64MB scores
  float* qf   = (float*)(ws + 144 * MBy);                     // alias S[0:32MB]
  float* kf   = (float*)(ws + 176 * MBy);                     // alias S[32:64MB]
  float* vf   = (float*)(ws + 208 * MBy);                     // alias P region
  unsigned short* P = (unsigned short*)(ws + 208 * MBy);      // 32MB

  const int n4 = 8192 * 1024 / 4;

  auto gemm = [&](const unsigned short* A, long long sAz,
                  const unsigned short* Bt, long long sBz, const float* bias,
                  float* Cf, long long sCfz, unsigned short* Cb, long long sCbz,
                  float* C2, int offc2, int M, int N, int K, int Z) {
    dim3 grid(N / 128, M / 128, Z);
    gemm_bt<<<grid, 256, 0, stream>>>((const short*)A, sAz, (const short*)Bt, sBz,
                                      bias, Cf, sCfz, (short*)Cb, sCbz, C2, offc2,
                                      M, N, K);
  };

  // casts
  cast_kernel<<<n4 / 256, 256, 0, stream>>>(q, ob, n4);  // qb lives in ob region
  cast_kernel<<<n4 / 256, 256, 0, stream>>>(k, kb, n4);
  cast_kernel<<<n4 / 256, 256, 0, stream>>>(v, vb, n4);
  for (int i = 0; i < 8; ++i)
    transpose_w_kernel<<<dim3(16, 16), 256, 0, stream>>>(W[i], WT + (size_t)i * 1024 * 1024);

  // ---- layer 1 ----
  gemm(ob, 0, WT + 0u * 1048576, 0, bW[0], qf, 0, 0, 0, res_p, 0,    8192, 1024, 1024, 1); // q1
  gemm(kb, 0, WT + 1u * 1048576, 0, bW[1], kf, 0, 0, 0, 0, 0,        8192, 1024, 1024, 1); // k1
  gemm(vb, 0, WT + 2u * 1048576, 0, bW[2], vf, 0, 0, 0, 0, 0,        8192, 1024, 1024, 1); // v1
  ln_kernel<<<8192, 256, 0, stream>>>(qf, g_[0], B_[0], lnq, 1.f / 32.f);
  ln_kernel<<<8192, 256, 0, stream>>>(kf, g_[1], B_[1], lnk, 1.f);
  ln_kernel<<<8192, 256, 0, stream>>>(vf, g_[2], B_[2], lnv, 1.f);
  transpose_v_kernel<<<dim3(16, 32, 4), 256, 0, stream>>>(lnv, lnvT);
  gemm(lnq, 2048ll * 1024, lnk, 2048ll * 1024, 0, Sbuf, 2048ll * 2048, 0, 0, 0, 0,
       2048, 2048, 1024, 4);                                           // S1
  softmax_kernel<<<8192, 256, 0, stream>>>(Sbuf, P, (float*)0);        // P1
  gemm(P, 2048ll * 2048, lnvT, 1024ll * 2048, 0, 0, 0, ob, 2048ll * 1024, 0, 0,
       2048, 1024, 2048, 4);                                           // o1 (bf16)
  gemm(ob, 0, WT + 3u * 1048576, 0, bW[3], 0, 0, ofb, 0, 0, 0, 8192, 1024, 1024, 1); // o1f

  // ---- layer 2 ----
  gemm(ofb, 0, WT + 4u * 1048576, 0, bW[4], qf, 0, 0, 0, res_p, 1024, 8192, 1024, 1024, 1); // q2
  gemm(kb, 0, WT + 5u * 1048576, 0, bW[5], kf, 0, 0, 0, 0, 0,         8192, 1024, 1024, 1); // k2
  gemm(vb, 0, WT + 6u * 1048576, 0, bW[6], vf, 0, 0, 0, 0, 0,         8192, 1024, 1024, 1); // v2
  ln_kernel<<<8192, 256, 0, stream>>>(qf, g_[3], B_[3], lnq, 1.f / 32.f);
  ln_kernel<<<8192, 256, 0, stream>>>(kf, g_[4], B_[4], lnk, 1.f);
  ln_kernel<<<8192, 256, 0, stream>>>(vf, g_[5], B_[5], lnv, 1.f);
  transpose_v_kernel<<<dim3(16, 32, 4), 256, 0, stream>>>(lnv, lnvT);
  gemm(lnq, 2048ll * 1024, lnk, 2048ll * 1024, 0, Sbuf, 2048ll * 2048, 0, 0, 0, 0,
       2048, 2048, 1024, 4);                                           // S2
  softmax_kernel<<<8192, 256, 0, stream>>>(Sbuf, P, a2_p);             // P2 + a2 out
  gemm(P, 2048ll * 2048, lnvT, 1024ll * 2048, 0, 0, 0, ob, 2048ll * 1024, 0, 0,
       2048, 1024, 2048, 4);                                           // o2 (bf16)
  gemm(ob, 0, WT + 7u * 1048576, 0, bW[7], out_p, 0, 0, 0, 0, 0, 8192, 1024, 1024, 1); // out
}

// Round 2
// 1003.670 us; speedup vs baseline: 1.0588x; 1.0588x over previous
//
#include <hip/hip_runtime.h>

#define DEV __device__ __forceinline__

using short8  = __attribute__((ext_vector_type(8))) short;
using floatx4 = __attribute__((ext_vector_type(4))) float;

// f32 -> bf16 round-to-nearest-even on raw bits
DEV unsigned short f2bf(float f) {
  unsigned int u = __float_as_uint(f);
  u += 0x7FFFu + ((u >> 16) & 1u);
  return (unsigned short)(u >> 16);
}

DEV void stage16(void* lds, const void* g) {
#if defined(__has_builtin) && __has_builtin(__builtin_amdgcn_global_load_lds)
  __builtin_amdgcn_global_load_lds(
      (__attribute__((address_space(1))) void*)g,
      (__attribute__((address_space(3))) void*)lds, 16, 0, 0);
#else
  *(int4*)lds = *(const int4*)g;
#endif
}

DEV float wave_sum(float x) {
#pragma unroll
  for (int m = 32; m; m >>= 1) x += __shfl_xor(x, m);
  return x;
}
DEV float wave_max(float x) {
#pragma unroll
  for (int m = 32; m; m >>= 1) x = fmaxf(x, __shfl_xor(x, m));
  return x;
}

// ---------------------------------------------------------------------------
// GEMM: C[z] = A[z] (MxK, K-major) * Bt[z]^T (Bt is NxK, K-major) [+ bias]
// Optional outputs: Cf (f32, ld=N), Cb (bf16, ld=N), C2 (f32, ld=2048, +offc2)
// ---------------------------------------------------------------------------
#define BM 128
#define BN 128
#define BK 32

__global__ __launch_bounds__(256)
void gemm_bt(const short* __restrict__ A, long long sAz,
             const short* __restrict__ Bt, long long sBz,
             const float* __restrict__ bias,
             float* __restrict__ Cf, long long sCfz,
             short* __restrict__ Cb, long long sCbz,
             float* __restrict__ C2, int offc2,
             int M, int N, int K) {
  const int z = blockIdx.z;
  A  += (long long)z * sAz;
  Bt += (long long)z * sBz;
  float* Cfz = Cf ? Cf + (long long)z * sCfz : (float*)0;
  short* Cbz = Cb ? Cb + (long long)z * sCbz : (short*)0;

  const int m0 = blockIdx.y * BM;
  const int n0 = blockIdx.x * BN;

  __shared__ __align__(16) short As[BM * BK];
  __shared__ __align__(16) short Bs[BN * BK];

  const int t    = threadIdx.x;
  const int lane = t & 63;
  const int w    = t >> 6;
  const int wr   = (w >> 1) * 64;
  const int wc   = (w & 1) * 64;
  const int mr   = lane & 15;
  const int kq   = lane >> 4;

  floatx4 acc[4][4];
#pragma unroll
  for (int i = 0; i < 4; ++i)
#pragma unroll
    for (int j = 0; j < 4; ++j)
      acc[i][j] = (floatx4){0.f, 0.f, 0.f, 0.f};

  for (int k0 = 0; k0 < K; k0 += BK) {
#pragma unroll
    for (int i = 0; i < 2; ++i) {
      const int c   = t + i * 256;
      const int row = c >> 2;
      const int cc  = c & 3;
      stage16(&As[c * 8], A  + (size_t)(m0 + row) * K + k0 + cc * 8);
      stage16(&Bs[c * 8], Bt + (size_t)(n0 + row) * K + k0 + cc * 8);
    }
    __syncthreads();

    short8 af[4], bf[4];
#pragma unroll
    for (int i = 0; i < 4; ++i)
      af[i] = *(const short8*)&As[(wr + i * 16 + mr) * BK + kq * 8];
#pragma unroll
    for (int j = 0; j < 4; ++j)
      bf[j] = *(const short8*)&Bs[(wc + j * 16 + mr) * BK + kq * 8];
#pragma unroll
    for (int i = 0; i < 4; ++i)
#pragma unroll
      for (int j = 0; j < 4; ++j)
        acc[i][j] = __builtin_amdgcn_mfma_f32_16x16x32_bf16(af[i], bf[j], acc[i][j], 0, 0, 0);
    __syncthreads();
  }

  // D layout: col=lane&15, row=(lane>>4)*4+reg  [measured m89/m91]
#pragma unroll
  for (int i = 0; i < 4; ++i) {
#pragma unroll
    for (int r = 0; r < 4; ++r) {
      const int row = m0 + wr + i * 16 + kq * 4 + r;
#pragma unroll
      for (int j = 0; j < 4; ++j) {
        const int col = n0 + wc + j * 16 + mr;
        float vv = acc[i][j][r];
        if (bias) vv += bias[col];
        if (Cfz) Cfz[(size_t)row * N + col] = vv;
        if (Cbz) Cbz[(size_t)row * N + col] = (short)f2bf(vv);
        if (C2)  C2[(size_t)row * 2048 + offc2 + col] = vv;
      }
    }
  }
}

// ---------------------------------------------------------------------------
// Multi-job LayerNorm over D=1024, f32 in (opt. +bias before stats) -> bf16
// ---------------------------------------------------------------------------
struct LnJob {
  const float* x;      // row base (col offset pre-folded)
  const float* bias;   // optional, length 1024 (added before stats)
  const float* g;
  const float* Bb;
  unsigned short* y;   // ld = 1024
  int ldx;
  float scale;
};

__global__ __launch_bounds__(256)
void ln_multi(LnJob j0, LnJob j1, LnJob j2, LnJob j3, LnJob j4) {
  LnJob jb = j0;
  if (blockIdx.y == 1) jb = j1;
  else if (blockIdx.y == 2) jb = j2;
  else if (blockIdx.y == 3) jb = j3;
  else if (blockIdx.y == 4) jb = j4;
  const int row = blockIdx.x, t = threadIdx.x;
  float4 v = ((const float4*)(jb.x + (size_t)row * jb.ldx))[t];
  if (jb.bias) {
    const float4 b4 = ((const float4*)jb.bias)[t];
    v.x += b4.x; v.y += b4.y; v.z += b4.z; v.w += b4.w;
  }
  float s  = v.x + v.y + v.z + v.w;
  float s2 = v.x * v.x + v.y * v.y + v.z * v.z + v.w * v.w;
  s = wave_sum(s);
  s2 = wave_sum(s2);
  __shared__ float r1[4], r2[4];
  const int w = t >> 6, lane = t & 63;
  if (!lane) { r1[w] = s; r2[w] = s2; }
  __syncthreads();
  s  = r1[0] + r1[1] + r1[2] + r1[3];
  s2 = r2[0] + r2[1] + r2[2] + r2[3];
  const float mean = s * (1.f / 1024.f);
  const float var  = s2 * (1.f / 1024.f) - mean * mean;
  const float rstd = 1.f / sqrtf(var + 1e-6f);
  const float4 g4 = ((const float4*)jb.g)[t];
  const float4 b4 = ((const float4*)jb.Bb)[t];
  ushort4 o;
  o.x = f2bf(((v.x - mean) * rstd * g4.x + b4.x) * jb.scale);
  o.y = f2bf(((v.y - mean) * rstd * g4.y + b4.y) * jb.scale);
  o.z = f2bf(((v.z - mean) * rstd * g4.z + b4.z) * jb.scale);
  o.w = f2bf(((v.w - mean) * rstd * g4.w + b4.w) * jb.scale);
  ((ushort4*)(jb.y + (size_t)row * 1024))[t] = o;
}

// ---------------------------------------------------------------------------
// Row softmax over 2048 f32 -> bf16 P (+ optional f32 copy for a2 output)
// ---------------------------------------------------------------------------
__global__ __launch_bounds__(256)
void softmax_kernel(const float* __restrict__ S, unsigned short* __restrict__ P,
                    float* __restrict__ A2) {
  const int row = blockIdx.x, t = threadIdx.x;
  const float4* sr = (const float4*)(S + (size_t)row * 2048);
  float4 a = sr[t], b = sr[t + 256];
  float m = fmaxf(fmaxf(fmaxf(a.x, a.y), fmaxf(a.z, a.w)),
                  fmaxf(fmaxf(b.x, b.y), fmaxf(b.z, b.w)));
  m = wave_max(m);
  __shared__ float red[4];
  const int w = t >> 6, lane = t & 63;
  if (!lane) red[w] = m;
  __syncthreads();
  m = fmaxf(fmaxf(red[0], red[1]), fmaxf(red[2], red[3]));
  a.x = expf(a.x - m); a.y = expf(a.y - m); a.z = expf(a.z - m); a.w = expf(a.w - m);
  b.x = expf(b.x - m); b.y = expf(b.y - m); b.z = expf(b.z - m); b.w = expf(b.w - m);
  float s = a.x + a.y + a.z + a.w + b.x + b.y + b.z + b.w;
  s = wave_sum(s);
  __syncthreads();
  if (!lane) red[w] = s;
  __syncthreads();
  s = red[0] + red[1] + red[2] + red[3];
  const float inv = 1.f / s;
  a.x *= inv; a.y *= inv; a.z *= inv; a.w *= inv;
  b.x *= inv; b.y *= inv; b.z *= inv; b.w *= inv;
  ushort4 o0, o1;
  o0.x = f2bf(a.x); o0.y = f2bf(a.y); o0.z = f2bf(a.z); o0.w = f2bf(a.w);
  o1.x = f2bf(b.x); o1.y = f2bf(b.y); o1.z = f2bf(b.z); o1.w = f2bf(b.w);
  ((ushort4*)(P + (size_t)row * 2048))[t] = o0;
  ((ushort4*)(P + (size_t)row * 2048))[t + 256] = o1;
  if (A2) {
    float4* ar = (float4*)(A2 + (size_t)row * 2048);
    ar[t] = a;
    ar[t + 256] = b;
  }
}

// ---------------------------------------------------------------------------
// f32 -> bf16 cast, 3 tensors in one dispatch
// ---------------------------------------------------------------------------
__global__ __launch_bounds__(256)
void cast3_kernel(const float* __restrict__ x0, const float* __restrict__ x1,
                  const float* __restrict__ x2, unsigned short* __restrict__ y0,
                  unsigned short* __restrict__ y1, unsigned short* __restrict__ y2) {
  const float* x = blockIdx.y == 0 ? x0 : (blockIdx.y == 1 ? x1 : x2);
  unsigned short* y = blockIdx.y == 0 ? y0 : (blockIdx.y == 1 ? y1 : y2);
  const int i = blockIdx.x * 256 + threadIdx.x;
  const float4 v = ((const float4*)x)[i];
  ushort4 o;
  o.x = f2bf(v.x); o.y = f2bf(v.y); o.z = f2bf(v.z); o.w = f2bf(v.w);
  ((ushort4*)y)[i] = o;
}

// ---------------------------------------------------------------------------
// 8x batched: W (1024x1024 f32) -> W^T (1024x1024 bf16)
// ---------------------------------------------------------------------------
struct W8 {
  const float* src[8];
  unsigned short* dst[8];
};

__global__ __launch_bounds__(256)
void transpose_w8_kernel(W8 p) {
  __shared__ unsigned short tile[64][65];
  const float* in = p.src[blockIdx.z];
  unsigned short* out = p.dst[blockIdx.z];
  const int tr0 = blockIdx.y * 64, tc0 = blockIdx.x * 64;
  const int x = threadIdx.x & 63, y = threadIdx.x >> 6;
#pragma unroll
  for (int i = 0; i < 16; ++i) {
    const int r = i * 4 + y;
    tile[r][x] = f2bf(in[(size_t)(tr0 + r) * 1024 + tc0 + x]);
  }
  __syncthreads();
#pragma unroll
  for (int i = 0; i < 16; ++i) {
    const int r = i * 4 + y;
    out[(size_t)(tc0 + r) * 1024 + tr0 + x] = tile[x][r];
  }
}

// ---------------------------------------------------------------------------
// bf16 transpose (z,2048,1024)->(z,1024,2048); z<4 from in0/out0, else in1/out1
// ---------------------------------------------------------------------------
__global__ __launch_bounds__(256)
void transpose_v8_kernel(const unsigned short* __restrict__ in0,
                         const unsigned short* __restrict__ in1,
                         unsigned short* __restrict__ out0,
                         unsigned short* __restrict__ out1) {
  __shared__ unsigned short tile[64][65];
  const int zz = blockIdx.z & 3;
  const unsigned short* in = (blockIdx.z < 4 ? in0 : in1) + (size_t)zz * 2048 * 1024;
  unsigned short* out = (blockIdx.z < 4 ? out0 : out1) + (size_t)zz * 1024 * 2048;
  const int tr0 = blockIdx.y * 64, tc0 = blockIdx.x * 64;
  const int x = threadIdx.x & 63, y = threadIdx.x >> 6;
#pragma unroll
  for (int i = 0; i < 16; ++i) {
    const int r = i * 4 + y;
    tile[r][x] = in[(size_t)(tr0 + r) * 1024 + tc0 + x];
  }
  __syncthreads();
#pragma unroll
  for (int i = 0; i < 16; ++i) {
    const int r = i * 4 + y;
    out[(size_t)(tc0 + r) * 2048 + tr0 + x] = tile[x][r];
  }
}

// ---------------------------------------------------------------------------
extern "C" void kernel_launch(void* const* d_in, const int* in_sizes, int n_in,
                              void* d_out, int out_size, void* d_ws, size_t ws_size,
                              hipStream_t stream) {
  const float* q = (const float*)d_in[0];
  const float* k = (const float*)d_in[1];
  const float* v = (const float*)d_in[2];
  const float* W[8];
  const float* bW[8];
  for (int i = 0; i < 8; ++i) {
    W[i]  = (const float*)d_in[3 + 2 * i];
    bW[i] = (const float*)d_in[4 + 2 * i];
  }
  const float* g_[6];
  const float* B_[6];
  for (int i = 0; i < 6; ++i) {
    g_[i] = (const float*)d_in[19 + 2 * i];
    B_[i] = (const float*)d_in[20 + 2 * i];
  }

  float* out_p = (float*)d_out;          // (4,2048,1024)
  float* res_p = out_p + 8388608;        // (8192,2048)
  float* a2_p  = res_p + 16777216;       // (4,2048,2048)

  // workspace layout (368 MB)
  char* ws = (char*)d_ws;
  const size_t MBy = 1u << 20;
  unsigned short* WqT1  = (unsigned short*)(ws + 0 * MBy);
  unsigned short* WfT1  = (unsigned short*)(ws + 2 * MBy);
  unsigned short* WqT2  = (unsigned short*)(ws + 4 * MBy);
  unsigned short* WfT2  = (unsigned short*)(ws + 6 * MBy);
  unsigned short* WkT12 = (unsigned short*)(ws + 8 * MBy);   // [Wk1^T ; Wk2^T] 2048x1024
  unsigned short* WvT12 = (unsigned short*)(ws + 12 * MBy);  // [Wv1^T ; Wv2^T]
  unsigned short* qb    = (unsigned short*)(ws + 16 * MBy);
  unsigned short* kb    = (unsigned short*)(ws + 32 * MBy);  // kb,vb contiguous (Z=2 stride)
  unsigned short* vb    = (unsigned short*)(ws + 48 * MBy);
  float* kf   = (float*)(ws + 64 * MBy);                     // (8192,2048): k1|k2
  float* vf   = (float*)(ws + 128 * MBy);                    // (8192,2048): v1|v2
  float* Sbuf = (float*)(ws + 64 * MBy);                     // alias kf (dead after LNs)
  unsigned short* P = (unsigned short*)(ws + 128 * MBy);     // alias vf
  float* qf   = (float*)(ws + 192 * MBy);                    // (8192,1024)
  unsigned short* lnq   = (unsigned short*)(ws + 224 * MBy);
  unsigned short* lnk1  = (unsigned short*)(ws + 240 * MBy);
  unsigned short* lnk2  = (unsigned short*)(ws + 256 * MBy);
  unsigned short* lnv1  = (unsigned short*)(ws + 272 * MBy);
  unsigned short* lnv2  = (unsigned short*)(ws + 288 * MBy);
  unsigned short* lnvT1 = (unsigned short*)(ws + 304 * MBy);
  unsigned short* lnvT2 = (unsigned short*)(ws + 320 * MBy);
  unsigned short* ofb   = (unsigned short*)(ws + 336 * MBy);
  unsigned short* ob    = (unsigned short*)(ws + 352 * MBy);

  auto gemm = [&](const unsigned short* A, long long sAz,
                  const unsigned short* Bt, long long sBz, const float* bias,
                  float* Cf, long long sCfz, unsigned short* Cb, long long sCbz,
                  float* C2, int offc2, int M, int N, int K, int Z) {
    dim3 grid(N / 128, M / 128, Z);
    gemm_bt<<<grid, 256, 0, stream>>>((const short*)A, sAz, (const short*)Bt, sBz,
                                      bias, Cf, sCfz, (short*)Cb, sCbz, C2, offc2,
                                      M, N, K);
  };
  LnJob nil{};

  // ---- prep ----
  cast3_kernel<<<dim3(8192, 3), 256, 0, stream>>>(q, k, v, qb, kb, vb);
  W8 w8;
  w8.src[0] = W[0]; w8.dst[0] = WqT1;
  w8.src[1] = W[1]; w8.dst[1] = WkT12;
  w8.src[2] = W[2]; w8.dst[2] = WvT12;
  w8.src[3] = W[3]; w8.dst[3] = WfT1;
  w8.src[4] = W[4]; w8.dst[4] = WqT2;
  w8.src[5] = W[5]; w8.dst[5] = WkT12 + 1024 * 1024;
  w8.src[6] = W[6]; w8.dst[6] = WvT12 + 1024 * 1024;
  w8.src[7] = W[7]; w8.dst[7] = WfT2;
  transpose_w8_kernel<<<dim3(16, 16, 8), 256, 0, stream>>>(w8);

  // ---- projections: k1|k2, v1|v2 (Z=2, N=2048, bias folded into LN); q1 ----
  gemm(kb, 8192ll * 1024, WkT12, 2048ll * 1024, 0, kf, 8192ll * 2048, 0, 0, 0, 0,
       8192, 2048, 1024, 2);
  gemm(qb, 0, WqT1, 0, bW[0], qf, 0, 0, 0, res_p, 0, 8192, 1024, 1024, 1);

  // ---- all 5 first-phase LayerNorms in one dispatch ----
  {
    LnJob jk1{kf,        bW[1], g_[1], B_[1], lnk1, 2048, 1.f};
    LnJob jk2{kf + 1024, bW[5], g_[4], B_[4], lnk2, 2048, 1.f};
    LnJob jv1{vf,        bW[2], g_[2], B_[2], lnv1, 2048, 1.f};
    LnJob jv2{vf + 1024, bW[6], g_[5], B_[5], lnv2, 2048, 1.f};
    LnJob jq1{qf,        0,     g_[0], B_[0], lnq,  1024, 1.f / 32.f};
    ln_multi<<<dim3(8192, 5), 256, 0, stream>>>(jk1, jk2, jv1, jv2, jq1);
  }
  transpose_v8_kernel<<<dim3(16, 32, 8), 256, 0, stream>>>(lnv1, lnv2, lnvT1, lnvT2);

  // ---- layer 1 attention ----
  gemm(lnq, 2048ll * 1024, lnk1, 2048ll * 1024, 0, Sbuf, 2048ll * 2048, 0, 0, 0, 0,
       2048, 2048, 1024, 4);
  softmax_kernel<<<8192, 256, 0, stream>>>(Sbuf, P, (float*)0);
  gemm(P, 2048ll * 2048, lnvT1, 1024ll * 2048, 0, 0, 0, ob, 2048ll * 1024, 0, 0,
       2048, 1024, 2048, 4);
  gemm(ob, 0, WfT1, 0, bW[3], 0, 0, ofb, 0, 0, 0, 8192, 1024, 1024, 1);

  // ---- layer 2 ----
  gemm(ofb, 0, WqT2, 0, bW[4], qf, 0, 0, 0, res_p, 1024, 8192, 1024, 1024, 1);
  {
    LnJob jq2{qf, 0, g_[3], B_[3], lnq, 1024, 1.f / 32.f};
    ln_multi<<<dim3(8192, 1), 256, 0, stream>>>(jq2, nil, nil, nil, nil);
  }
  gemm(lnq, 2048ll * 1024, lnk2, 2048ll * 1024, 0, Sbuf, 2048ll * 2048, 0, 0, 0, 0,
       2048, 2048, 1024, 4);
  softmax_kernel<<<8192, 256, 0, stream>>>(Sbuf, P, a2_p);
  gemm(P, 2048ll * 2048, lnvT2, 1024ll * 2048, 0, 0, 0, ob, 2048ll * 1024, 0, 0,
       2048, 1024, 2048, 4);
  gemm(ob, 0, WfT2, 0, bW[7], out_p, 0, 0, 0, 0, 0, 8192, 1024, 1024, 1);
}

// Round 3
// 981.024 us; speedup vs baseline: 1.0833x; 1.0231x over previous
//
#include <hip/hip_runtime.h>

#define DEV __device__ __forceinline__

using short8  = __attribute__((ext_vector_type(8))) short;
using floatx4 = __attribute__((ext_vector_type(4))) float;

DEV unsigned short f2bf(float f) {
  unsigned int u = __float_as_uint(f);
  u += 0x7FFFu + ((u >> 16) & 1u);
  return (unsigned short)(u >> 16);
}
DEV float bf2f(unsigned short u) { return __uint_as_float(((unsigned int)u) << 16); }

DEV void stage16(void* lds, const void* g) {
  __builtin_amdgcn_global_load_lds(
      (__attribute__((address_space(1))) void*)g,
      (__attribute__((address_space(3))) void*)lds, 16, 0, 0);
}

DEV float wave_sum(float x) {
#pragma unroll
  for (int m = 32; m; m >>= 1) x += __shfl_xor(x, m);
  return x;
}
DEV float wave_max(float x) {
#pragma unroll
  for (int m = 32; m; m >>= 1) x = fmaxf(x, __shfl_xor(x, m));
  return x;
}

// ---------------------------------------------------------------------------
// 128x128 tile GEMM core: C = A (MxK, K-major) * Bt^T (Bt NxK, K-major)
// LDS K-chunk XOR swizzle: cell (row, cc) holds global chunk cc^((row>>1)&3)
// -> fragment ds_read_b128 spreads over 8 bank-group starts (2-way, free).
// Outputs optional: Cf (f32 ld N), Cb (bf16 ld N), C2 (f32 ld 2048 + offc2).
// ---------------------------------------------------------------------------
DEV void gemm_core(const short* __restrict__ A, const short* __restrict__ Bt,
                   const float* __restrict__ bias,
                   float* __restrict__ Cf, unsigned short* __restrict__ Cb,
                   float* __restrict__ C2, int offc2,
                   int N, int K, int m0, int n0) {
  __shared__ __align__(16) short As[128 * 32];
  __shared__ __align__(16) short Bs[128 * 32];

  const int t    = threadIdx.x;
  const int lane = t & 63;
  const int w    = t >> 6;
  const int wr   = (w >> 1) * 64;
  const int wc   = (w & 1) * 64;
  const int mr   = lane & 15;
  const int kq   = lane >> 4;
  const int ca   = kq ^ ((mr >> 1) & 3);   // swizzled fragment chunk

  floatx4 acc[4][4];
#pragma unroll
  for (int i = 0; i < 4; ++i)
#pragma unroll
    for (int j = 0; j < 4; ++j)
      acc[i][j] = (floatx4){0.f, 0.f, 0.f, 0.f};

  for (int k0 = 0; k0 < K; k0 += 32) {
#pragma unroll
    for (int i = 0; i < 2; ++i) {
      const int c   = t + i * 256;
      const int row = c >> 2;
      const int cc  = c & 3;
      const int sc  = cc ^ ((row >> 1) & 3);   // swizzled source chunk
      stage16(&As[c * 8], A  + (size_t)(m0 + row) * K + k0 + sc * 8);
      stage16(&Bs[c * 8], Bt + (size_t)(n0 + row) * K + k0 + sc * 8);
    }
    __syncthreads();

    short8 af[4], bf4[4];
#pragma unroll
    for (int i = 0; i < 4; ++i)
      af[i] = *(const short8*)&As[(wr + i * 16 + mr) * 32 + ca * 8];
#pragma unroll
    for (int j = 0; j < 4; ++j)
      bf4[j] = *(const short8*)&Bs[(wc + j * 16 + mr) * 32 + ca * 8];
#pragma unroll
    for (int i = 0; i < 4; ++i)
#pragma unroll
      for (int j = 0; j < 4; ++j)
        acc[i][j] = __builtin_amdgcn_mfma_f32_16x16x32_bf16(af[i], bf4[j], acc[i][j], 0, 0, 0);
    __syncthreads();
  }

  // D layout: col=lane&15, row=(lane>>4)*4+reg  [measured m89/m91]
#pragma unroll
  for (int i = 0; i < 4; ++i) {
#pragma unroll
    for (int r = 0; r < 4; ++r) {
      const int row = m0 + wr + i * 16 + kq * 4 + r;
#pragma unroll
      for (int j = 0; j < 4; ++j) {
        const int col = n0 + wc + j * 16 + mr;
        float vv = acc[i][j][r];
        if (bias) vv += bias[col];
        if (Cf) Cf[(size_t)row * N + col] = vv;
        if (Cb) Cb[(size_t)row * N + col] = f2bf(vv);
        if (C2) C2[(size_t)row * 2048 + offc2 + col] = vv;
      }
    }
  }
}

__global__ __launch_bounds__(256)
void gemm_bt(const short* __restrict__ A, long long sAz,
             const short* __restrict__ Bt, long long sBz,
             const float* __restrict__ bias,
             float* __restrict__ Cf, long long sCfz,
             unsigned short* __restrict__ Cb, long long sCbz,
             float* __restrict__ C2, int offc2,
             int N, int K) {
  const int z = blockIdx.z;
  gemm_core(A + (long long)z * sAz, Bt + (long long)z * sBz, bias,
            Cf ? Cf + (long long)z * sCfz : (float*)0,
            Cb ? Cb + (long long)z * sCbz : (unsigned short*)0,
            C2, offc2, N, K, blockIdx.y * 128, blockIdx.x * 128);
}

// 5 independent projection jobs in one dispatch (M=8192, N=1024, K=1024 each)
struct ProjJob {
  const short* A;
  const short* Bt;
  const float* bias;
  unsigned short* Cb;
  float* C2;
  long long offc2;
};
struct Proj5 { ProjJob j[5]; };

__global__ __launch_bounds__(256)
void gemm_proj5(Proj5 p) {
  ProjJob jb = p.j[0];
#pragma unroll
  for (int i = 1; i < 5; ++i)
    if ((int)blockIdx.z == i) jb = p.j[i];
  gemm_core(jb.A, jb.Bt, jb.bias, (float*)0, jb.Cb, jb.C2, (int)jb.offc2,
            1024, 1024, blockIdx.y * 128, blockIdx.x * 128);
}

// ---------------------------------------------------------------------------
// Multi-job LayerNorm over D=1024, bf16 in (opt. +f32 bias before stats) -> bf16
// ---------------------------------------------------------------------------
struct LnJob {
  const unsigned short* x;  // ld = 1024
  const float* bias;        // optional, added before stats
  const float* g;
  const float* Bb;
  unsigned short* y;        // ld = 1024
  float scale;
};

__global__ __launch_bounds__(256)
void ln_multi(LnJob j0, LnJob j1, LnJob j2, LnJob j3, LnJob j4) {
  LnJob jb = j0;
  if (blockIdx.y == 1) jb = j1;
  else if (blockIdx.y == 2) jb = j2;
  else if (blockIdx.y == 3) jb = j3;
  else if (blockIdx.y == 4) jb = j4;
  const int row = blockIdx.x, t = threadIdx.x;
  const ushort4 xv = ((const ushort4*)(jb.x + (size_t)row * 1024))[t];
  float4 v = {bf2f(xv.x), bf2f(xv.y), bf2f(xv.z), bf2f(xv.w)};
  if (jb.bias) {
    const float4 b4 = ((const float4*)jb.bias)[t];
    v.x += b4.x; v.y += b4.y; v.z += b4.z; v.w += b4.w;
  }
  float s  = v.x + v.y + v.z + v.w;
  float s2 = v.x * v.x + v.y * v.y + v.z * v.z + v.w * v.w;
  s = wave_sum(s);
  s2 = wave_sum(s2);
  __shared__ float r1[4], r2[4];
  const int w = t >> 6, lane = t & 63;
  if (!lane) { r1[w] = s; r2[w] = s2; }
  __syncthreads();
  s  = r1[0] + r1[1] + r1[2] + r1[3];
  s2 = r2[0] + r2[1] + r2[2] + r2[3];
  const float mean = s * (1.f / 1024.f);
  const float var  = s2 * (1.f / 1024.f) - mean * mean;
  const float rstd = 1.f / sqrtf(var + 1e-6f);
  const float4 g4 = ((const float4*)jb.g)[t];
  const float4 b4 = ((const float4*)jb.Bb)[t];
  ushort4 o;
  o.x = f2bf(((v.x - mean) * rstd * g4.x + b4.x) * jb.scale);
  o.y = f2bf(((v.y - mean) * rstd * g4.y + b4.y) * jb.scale);
  o.z = f2bf(((v.z - mean) * rstd * g4.z + b4.z) * jb.scale);
  o.w = f2bf(((v.w - mean) * rstd * g4.w + b4.w) * jb.scale);
  ((ushort4*)(jb.y + (size_t)row * 1024))[t] = o;
}

// ---------------------------------------------------------------------------
// Row softmax over 2048 f32 -> bf16 P (+ optional f32 a2 copy)
// ---------------------------------------------------------------------------
__global__ __launch_bounds__(256)
void softmax_kernel(const float* __restrict__ S, unsigned short* __restrict__ P,
                    float* __restrict__ A2) {
  const int row = blockIdx.x, t = threadIdx.x;
  const float4* sr = (const float4*)(S + (size_t)row * 2048);
  float4 a = sr[t], b = sr[t + 256];
  float m = fmaxf(fmaxf(fmaxf(a.x, a.y), fmaxf(a.z, a.w)),
                  fmaxf(fmaxf(b.x, b.y), fmaxf(b.z, b.w)));
  m = wave_max(m);
  __shared__ float red[4];
  const int w = t >> 6, lane = t & 63;
  if (!lane) red[w] = m;
  __syncthreads();
  m = fmaxf(fmaxf(red[0], red[1]), fmaxf(red[2], red[3]));
  a.x = __expf(a.x - m); a.y = __expf(a.y - m); a.z = __expf(a.z - m); a.w = __expf(a.w - m);
  b.x = __expf(b.x - m); b.y = __expf(b.y - m); b.z = __expf(b.z - m); b.w = __expf(b.w - m);
  float s = a.x + a.y + a.z + a.w + b.x + b.y + b.z + b.w;
  s = wave_sum(s);
  __syncthreads();
  if (!lane) red[w] = s;
  __syncthreads();
  s = red[0] + red[1] + red[2] + red[3];
  const float inv = 1.f / s;
  a.x *= inv; a.y *= inv; a.z *= inv; a.w *= inv;
  b.x *= inv; b.y *= inv; b.z *= inv; b.w *= inv;
  ushort4 o0, o1;
  o0.x = f2bf(a.x); o0.y = f2bf(a.y); o0.z = f2bf(a.z); o0.w = f2bf(a.w);
  o1.x = f2bf(b.x); o1.y = f2bf(b.y); o1.z = f2bf(b.z); o1.w = f2bf(b.w);
  ((ushort4*)(P + (size_t)row * 2048))[t] = o0;
  ((ushort4*)(P + (size_t)row * 2048))[t + 256] = o1;
  if (A2) {
    float4* ar = (float4*)(A2 + (size_t)row * 2048);
    ar[t] = a;
    ar[t + 256] = b;
  }
}

// ---------------------------------------------------------------------------
__global__ __launch_bounds__(256)
void cast3_kernel(const float* __restrict__ x0, const float* __restrict__ x1,
                  const float* __restrict__ x2, unsigned short* __restrict__ y0,
                  unsigned short* __restrict__ y1, unsigned short* __restrict__ y2) {
  const float* x = blockIdx.y == 0 ? x0 : (blockIdx.y == 1 ? x1 : x2);
  unsigned short* y = blockIdx.y == 0 ? y0 : (blockIdx.y == 1 ? y1 : y2);
  const int i = blockIdx.x * 256 + threadIdx.x;
  const float4 v = ((const float4*)x)[i];
  ushort4 o;
  o.x = f2bf(v.x); o.y = f2bf(v.y); o.z = f2bf(v.z); o.w = f2bf(v.w);
  ((ushort4*)y)[i] = o;
}

struct W8 {
  const float* src[8];
  unsigned short* dst[8];
};

__global__ __launch_bounds__(256)
void transpose_w8_kernel(W8 p) {
  __shared__ unsigned short tile[64][65];
  const float* in = p.src[blockIdx.z];
  unsigned short* out = p.dst[blockIdx.z];
  const int tr0 = blockIdx.y * 64, tc0 = blockIdx.x * 64;
  const int x = threadIdx.x & 63, y = threadIdx.x >> 6;
#pragma unroll
  for (int i = 0; i < 16; ++i) {
    const int r = i * 4 + y;
    tile[r][x] = f2bf(in[(size_t)(tr0 + r) * 1024 + tc0 + x]);
  }
  __syncthreads();
#pragma unroll
  for (int i = 0; i < 16; ++i) {
    const int r = i * 4 + y;
    out[(size_t)(tc0 + r) * 1024 + tr0 + x] = tile[x][r];
  }
}

__global__ __launch_bounds__(256)
void transpose_v8_kernel(const unsigned short* __restrict__ in0,
                         const unsigned short* __restrict__ in1,
                         unsigned short* __restrict__ out0,
                         unsigned short* __restrict__ out1) {
  __shared__ unsigned short tile[64][65];
  const int zz = blockIdx.z & 3;
  const unsigned short* in = (blockIdx.z < 4 ? in0 : in1) + (size_t)zz * 2048 * 1024;
  unsigned short* out = (blockIdx.z < 4 ? out0 : out1) + (size_t)zz * 1024 * 2048;
  const int tr0 = blockIdx.y * 64, tc0 = blockIdx.x * 64;
  const int x = threadIdx.x & 63, y = threadIdx.x >> 6;
#pragma unroll
  for (int i = 0; i < 16; ++i) {
    const int r = i * 4 + y;
    tile[r][x] = in[(size_t)(tr0 + r) * 1024 + tc0 + x];
  }
  __syncthreads();
#pragma unroll
  for (int i = 0; i < 16; ++i) {
    const int r = i * 4 + y;
    out[(size_t)(tc0 + r) * 2048 + tr0 + x] = tile[x][r];
  }
}

// ---------------------------------------------------------------------------
extern "C" void kernel_launch(void* const* d_in, const int* in_sizes, int n_in,
                              void* d_out, int out_size, void* d_ws, size_t ws_size,
                              hipStream_t stream) {
  const float* q = (const float*)d_in[0];
  const float* k = (const float*)d_in[1];
  const float* v = (const float*)d_in[2];
  const float* W[8];
  const float* bW[8];
  for (int i = 0; i < 8; ++i) {
    W[i]  = (const float*)d_in[3 + 2 * i];
    bW[i] = (const float*)d_in[4 + 2 * i];
  }
  const float* g_[6];
  const float* B_[6];
  for (int i = 0; i < 6; ++i) {
    g_[i] = (const float*)d_in[19 + 2 * i];
    B_[i] = (const float*)d_in[20 + 2 * i];
  }

  float* out_p = (float*)d_out;          // (4,2048,1024)
  float* res_p = out_p + 8388608;        // (8192,2048)
  float* a2_p  = res_p + 16777216;       // (4,2048,2048)

  // workspace layout (~338 MB)
  char* ws = (char*)d_ws;
  const size_t MBy = 1u << 20;
  unsigned short* WT   = (unsigned short*)ws;                 // 8 x 2MB
  unsigned short* qb   = (unsigned short*)(ws + 16 * MBy);
  unsigned short* kb   = (unsigned short*)(ws + 32 * MBy);
  unsigned short* vb   = (unsigned short*)(ws + 48 * MBy);
  unsigned short* pb   = (unsigned short*)(ws + 64 * MBy);    // 5 x 16MB proj slices
  float* Sbuf          = (float*)(ws + 64 * MBy);             // 67MB, aliases pb (dead after LN)
  unsigned short* lnq  = (unsigned short*)(ws + 144 * MBy);
  unsigned short* lnk1 = (unsigned short*)(ws + 160 * MBy);
  unsigned short* lnk2 = (unsigned short*)(ws + 176 * MBy);
  unsigned short* lnv1 = (unsigned short*)(ws + 192 * MBy);
  unsigned short* lnv2 = (unsigned short*)(ws + 208 * MBy);
  unsigned short* lnvT1= (unsigned short*)(ws + 224 * MBy);
  unsigned short* lnvT2= (unsigned short*)(ws + 240 * MBy);
  unsigned short* P    = (unsigned short*)(ws + 256 * MBy);   // 33MB
  unsigned short* ofb  = (unsigned short*)(ws + 290 * MBy);
  unsigned short* ob   = (unsigned short*)(ws + 306 * MBy);
  unsigned short* qf2b = (unsigned short*)(ws + 322 * MBy);

  const size_t SL = 8192ull * 1024;  // proj slice elements

  auto gemm = [&](const unsigned short* A, long long sAz,
                  const unsigned short* Bt, long long sBz, const float* bias,
                  float* Cf, long long sCfz, unsigned short* Cb, long long sCbz,
                  float* C2, int offc2, int M, int N, int K, int Z) {
    dim3 grid(N / 128, M / 128, Z);
    gemm_bt<<<grid, 256, 0, stream>>>((const short*)A, sAz, (const short*)Bt, sBz,
                                      bias, Cf, sCfz, Cb, sCbz, C2, offc2, N, K);
  };
  LnJob nil{};

  // ---- prep ----
  cast3_kernel<<<dim3(8192, 3), 256, 0, stream>>>(q, k, v, qb, kb, vb);
  W8 w8;
  for (int i = 0; i < 8; ++i) { w8.src[i] = W[i]; w8.dst[i] = WT + (size_t)i * 1048576; }
  transpose_w8_kernel<<<dim3(16, 16, 8), 256, 0, stream>>>(w8);

  // ---- all 5 projections in one dispatch (k1,k2,v1,v2,q1) ----
  {
    Proj5 p;
    p.j[0] = {(const short*)kb, (const short*)(WT + 1u * 1048576), 0, pb + 0 * SL, 0, 0};
    p.j[1] = {(const short*)kb, (const short*)(WT + 5u * 1048576), 0, pb + 1 * SL, 0, 0};
    p.j[2] = {(const short*)vb, (const short*)(WT + 2u * 1048576), 0, pb + 2 * SL, 0, 0};
    p.j[3] = {(const short*)vb, (const short*)(WT + 6u * 1048576), 0, pb + 3 * SL, 0, 0};
    p.j[4] = {(const short*)qb, (const short*)(WT + 0u * 1048576), bW[0], pb + 4 * SL, res_p, 0};
    gemm_proj5<<<dim3(8, 64, 5), 256, 0, stream>>>(p);
  }

  // ---- all 5 first-phase LayerNorms in one dispatch ----
  {
    LnJob jk1{pb + 0 * SL, bW[1], g_[1], B_[1], lnk1, 1.f};
    LnJob jk2{pb + 1 * SL, bW[5], g_[4], B_[4], lnk2, 1.f};
    LnJob jv1{pb + 2 * SL, bW[2], g_[2], B_[2], lnv1, 1.f};
    LnJob jv2{pb + 3 * SL, bW[6], g_[5], B_[5], lnv2, 1.f};
    LnJob jq1{pb + 4 * SL, 0,     g_[0], B_[0], lnq,  1.f / 32.f};
    ln_multi<<<dim3(8192, 5), 256, 0, stream>>>(jk1, jk2, jv1, jv2, jq1);
  }
  transpose_v8_kernel<<<dim3(16, 32, 8), 256, 0, stream>>>(lnv1, lnv2, lnvT1, lnvT2);

  // ---- layer 1 attention ----
  gemm(lnq, 2048ll * 1024, lnk1, 2048ll * 1024, 0, Sbuf, 2048ll * 2048, 0, 0, 0, 0,
       2048, 2048, 1024, 4);
  softmax_kernel<<<8192, 256, 0, stream>>>(Sbuf, P, (float*)0);
  gemm(P, 2048ll * 2048, lnvT1, 1024ll * 2048, 0, 0, 0, ob, 2048ll * 1024, 0, 0,
       2048, 1024, 2048, 4);
  gemm(ob, 0, WT + 3u * 1048576, 0, bW[3], 0, 0, ofb, 0, 0, 0, 8192, 1024, 1024, 1);

  // ---- layer 2 ----
  gemm(ofb, 0, WT + 4u * 1048576, 0, bW[4], 0, 0, qf2b, 0, res_p, 1024, 8192, 1024, 1024, 1);
  {
    LnJob jq2{qf2b, 0, g_[3], B_[3], lnq, 1.f / 32.f};
    ln_multi<<<dim3(8192, 1), 256, 0, stream>>>(jq2, nil, nil, nil, nil);
  }
  gemm(lnq, 2048ll * 1024, lnk2, 2048ll * 1024, 0, Sbuf, 2048ll * 2048, 0, 0, 0, 0,
       2048, 2048, 1024, 4);
  softmax_kernel<<<8192, 256, 0, stream>>>(Sbuf, P, a2_p);
  gemm(P, 2048ll * 2048, lnvT2, 1024ll * 2048, 0, 0, 0, ob, 2048ll * 1024, 0, 0,
       2048, 1024, 2048, 4);
  gemm(ob, 0, WT + 7u * 1048576, 0, bW[7], out_p, 0, 0, 0, 0, 0, 8192, 1024, 1024, 1);
}